// Round 6
// baseline (196.086 us; speedup 1.0000x reference)
//
#include <hip/hip_runtime.h>
#include <hip/hip_bf16.h>
#include <stdint.h>

// y = sum_{k=0}^{3} h_k * S^k X,  X [8192,128] f32, S [8192,8192] f32.
//   k_prep:      y = h0*X ; ZT0 = X^T bf16
//   pass 1:      k_gemm_cv2: each block linearly converts its own 64x(NN/KS)
//                f32 A-slice -> S16 (coalesced), then bf16 K-loop reads the
//                L2-hot S16 via global_load_lds. Writes P partials.
//   pass 2,3:    k_gemm_bf: bf16 K-loop on S16 (L3-resident).
//   after each:  k_combine: Z = sum_ks P ; y += h_k Z ; ZT' = bf16(Z^T).
// GEMM core (measured r3: ~23 us): BM=64,BN=128,BK=64, 512 thr (8 waves),
// global_load_lds(16B), XOR-swizzled LDS, 2-buffer counted-vmcnt pipeline.

typedef __attribute__((ext_vector_type(8))) short     bf16x8;
typedef __attribute__((ext_vector_type(8))) uint16_t  u16x8;
typedef __attribute__((ext_vector_type(4))) float     f32x4;

#define NN 8192
#define NF 128
#define ZSTRIDE (8192 + 64)

#define WAITV(n) asm volatile("s_waitcnt vmcnt(" #n ")" ::: "memory")
#define WAITL0   asm volatile("s_waitcnt lgkmcnt(0)" ::: "memory")

__device__ inline uint16_t f2bf(float f) {
    uint32_t u = __builtin_bit_cast(uint32_t, f);
    u += 0x7fffu + ((u >> 16) & 1u);     // round-to-nearest-even
    return (uint16_t)(u >> 16);
}

__device__ inline void gl2lds16(const void* g, uint8_t* l) {
    __builtin_amdgcn_global_load_lds(
        (const __attribute__((address_space(1))) uint32_t*)g,
        (__attribute__((address_space(3))) uint32_t*)l,
        16, 0, 0);
}

__device__ inline bf16x8 ld16(const uint8_t* p) {
    return __builtin_bit_cast(bf16x8, *(const u16x8*)p);
}

// ---- y = h0*X ; ZT0 = X^T bf16 --------------------------------------------
__global__ __launch_bounds__(256) void k_prep(const float* __restrict__ X,
                                              const float* __restrict__ coeff,
                                              float* __restrict__ y,
                                              uint16_t* __restrict__ ZT0) {
    __shared__ float tile[16][NF + 4];
    const int t  = threadIdx.x;
    const int r0 = blockIdx.x * 16;
    const float h0 = coeff[0];
#pragma unroll
    for (int i = 0; i < 2; ++i) {
        int o   = (i * 256 + t) * 4;
        int row = o >> 7, col = o & 127;
        f32x4 v = *(const f32x4*)(X + (size_t)(r0 + row) * NF + col);
        *(f32x4*)&tile[row][col] = v;
        *(f32x4*)(y + (size_t)(r0 + row) * NF + col) = v * h0;
    }
    __syncthreads();
    const int c = t >> 1, rh = t & 1;
    u16x8 pk;
#pragma unroll
    for (int e = 0; e < 8; ++e) pk[e] = f2bf(tile[rh * 8 + e][c]);
    *(u16x8*)(ZT0 + (size_t)c * ZSTRIDE + r0 + rh * 8) = pk;
}

// ---- shared GEMM core: 2-buffer counted-vmcnt K-loop -----------------------
// smem layout per buf: A 8KB | B 16KB.  Caller provides swizzled srcs.
template<int NT>
__device__ inline void gemm_core(const uint16_t* asrc, const uint16_t* bsrc,
                                 uint8_t* smem, int t, f32x4 (&acc)[4],
                                 int aoff, int bof) {
    auto stage = [&](int buf, int kt) {
        const int ko = kt * 64;
        uint8_t* b = smem + buf * 24576;
        gl2lds16(asrc + ko, b + t * 16);
        gl2lds16(bsrc + ko, b + 8192 + t * 16);
        gl2lds16(bsrc + (size_t)64 * ZSTRIDE + ko, b + 16384 + t * 16);
    };
    stage(0, 0);
    int cur = 0;
#pragma unroll 1
    for (int kt = 0; kt < NT; ++kt) {
        if (kt + 1 < NT) {
            stage(cur ^ 1, kt + 1);
            WAITV(3);                 // stage(kt) done; stage(kt+1) in flight
        } else {
            WAITV(0);
        }
        __builtin_amdgcn_s_barrier();
        __builtin_amdgcn_sched_barrier(0);
        const uint8_t* bb = smem + cur * 24576;
        bf16x8 a0 = ld16(bb + aoff);
        bf16x8 a1 = ld16(bb + (aoff ^ 64));
#pragma unroll
        for (int ct = 0; ct < 4; ++ct) {
            acc[ct] = __builtin_amdgcn_mfma_f32_16x16x32_bf16(
                a0, ld16(bb + bof + ct * 16 * 128), acc[ct], 0, 0, 0);
            acc[ct] = __builtin_amdgcn_mfma_f32_16x16x32_bf16(
                a1, ld16(bb + ((bof + ct * 16 * 128) ^ 64)), acc[ct], 0, 0, 0);
        }
        WAITL0;                       // my reads of buf landed
        __builtin_amdgcn_sched_barrier(0);
        __builtin_amdgcn_s_barrier(); // everyone done reading buf
        cur ^= 1;
    }
}

// ---- pass 2/3 GEMM: bf16 S16 ------------------------------------------------
template<int KS>
__global__ __launch_bounds__(512, 4) void k_gemm_bf(
    const uint16_t* __restrict__ S16, const uint16_t* __restrict__ ZTin,
    float* __restrict__ P)
{
    __shared__ __align__(16) uint8_t smem[2][24576];
    const int t = threadIdx.x, lane = t & 63;
    const int w = t >> 6, m = lane & 15, g = lane >> 4;
    const int rt = w & 3, ch = w >> 2;
    const int mt = blockIdx.x & 127, ks = blockIdx.x >> 7;
    const int r0 = mt * 64;
    const int kb = ks * (NN / KS);
    constexpr int NT = (NN / KS) / 64;

    const int srow = t >> 3, sc = t & 7;
    const int scs  = (sc ^ (srow & 7)) << 3;
    const uint16_t* asrc = S16  + (size_t)(r0 + srow) * NN + kb + scs;
    const uint16_t* bsrc = ZTin + (size_t)srow * ZSTRIDE   + kb + scs;

    const int sw   = m & 7;
    const int aoff = (rt * 16 + m) * 128 + ((g ^ sw) << 4);
    const int bof  = 8192 + (ch * 64 + m) * 128 + ((g ^ sw) << 4);

    f32x4 acc[4] = {};
    gemm_core<NT>(asrc, bsrc, &smem[0][0], t, acc, aoff, bof);

    float* pb = P + ((size_t)ks * NN + r0 + rt * 16 + 4 * g) * NF + ch * 64 + m;
#pragma unroll
    for (int ct = 0; ct < 4; ++ct)
#pragma unroll
        for (int i = 0; i < 4; ++i)
            pb[(size_t)i * NF + ct * 16] = acc[ct][i];
}

// ---- pass 1 GEMM: convert own A-slice (linear), then bf16 K-loop -----------
template<int KS>
__global__ __launch_bounds__(512, 4) void k_gemm_cv2(
    const float* __restrict__ Sf, const uint16_t* __restrict__ S16,
    const uint16_t* __restrict__ ZTin, float* __restrict__ P)
{
    __shared__ __align__(16) uint8_t smem[2][24576];
    const int t = threadIdx.x, lane = t & 63;
    const int w = t >> 6, m = lane & 15, g = lane >> 4;
    const int rt = w & 3, ch = w >> 2;
    const int mt = blockIdx.x & 127, ks = blockIdx.x >> 7;
    const int r0 = mt * 64;
    const int kb = ks * (NN / KS);
    constexpr int KSL = NN / KS;          // K-slice width
    constexpr int NT  = KSL / 64;
    constexpr int C8  = KSL / 8;          // 8-elem chunks per row
    constexpr int ITERS = 64 * KSL / (512 * 8);

    // phase 1: convert my block's 64 x KSL f32 slice -> S16 (fully coalesced)
    uint16_t* S16w = (uint16_t*)S16;      // write view
#pragma unroll 4
    for (int it = 0; it < ITERS; ++it) {
        int id  = it * 512 + t;
        int row = id / C8, c8 = id % C8;
        size_t off = (size_t)(r0 + row) * NN + kb + c8 * 8;
        f32x4 a = *(const f32x4*)(Sf + off);
        f32x4 b = *(const f32x4*)(Sf + off + 4);
        u16x8 p;
#pragma unroll
        for (int j = 0; j < 4; ++j) { p[j] = f2bf(a[j]); p[j + 4] = f2bf(b[j]); }
        *(u16x8*)(S16w + off) = p;
    }
    WAITV(0);                              // stores in L2
    __syncthreads();

    // phase 2: standard bf16 K-loop; A reads hit our freshly-written L2 lines
    const int srow = t >> 3, sc = t & 7;
    const int scs  = (sc ^ (srow & 7)) << 3;
    const uint16_t* asrc = S16  + (size_t)(r0 + srow) * NN + kb + scs;
    const uint16_t* bsrc = ZTin + (size_t)srow * ZSTRIDE   + kb + scs;

    const int sw   = m & 7;
    const int aoff = (rt * 16 + m) * 128 + ((g ^ sw) << 4);
    const int bof  = 8192 + (ch * 64 + m) * 128 + ((g ^ sw) << 4);

    f32x4 acc[4] = {};
    gemm_core<NT>(asrc, bsrc, &smem[0][0], t, acc, aoff, bof);

    float* pb = P + ((size_t)ks * NN + r0 + rt * 16 + 4 * g) * NF + ch * 64 + m;
#pragma unroll
    for (int ct = 0; ct < 4; ++ct)
#pragma unroll
        for (int i = 0; i < 4; ++i)
            pb[(size_t)i * NF + ct * 16] = acc[ct][i];
}

// ---- combine: Z = sum_ks P ; y += h*Z ; ZT' = bf16(Z^T) --------------------
template<int KS, bool WRITE_ZT>
__global__ __launch_bounds__(256) void k_combine(const float* __restrict__ P,
                                                 float* __restrict__ y,
                                                 uint16_t* __restrict__ ZTout,
                                                 const float* __restrict__ coeff,
                                                 int pass) {
    __shared__ float tile[16][NF + 4];
    const int t = threadIdx.x, r0 = blockIdx.x * 16;
    const float hk = coeff[pass];
    const int row = t >> 4, col = (t & 15) * 8;
    const size_t off = (size_t)(r0 + row) * NF + col;
    f32x4 s0 = *(const f32x4*)(P + off);
    f32x4 s1 = *(const f32x4*)(P + off + 4);
#pragma unroll
    for (int k = 1; k < KS; ++k) {
        s0 += *(const f32x4*)(P + (size_t)k * NN * NF + off);
        s1 += *(const f32x4*)(P + (size_t)k * NN * NF + off + 4);
    }
    float* yp = y + off;
    f32x4 y0 = *(const f32x4*)yp, y1 = *(const f32x4*)(yp + 4);
    *(f32x4*)yp       = y0 + hk * s0;
    *(f32x4*)(yp + 4) = y1 + hk * s1;
    if (WRITE_ZT) {
        *(f32x4*)&tile[row][col]     = s0;
        *(f32x4*)&tile[row][col + 4] = s1;
        __syncthreads();
        const int c = t >> 1, rh = t & 1;
        u16x8 pk;
#pragma unroll
        for (int e = 0; e < 8; ++e) pk[e] = f2bf(tile[rh * 8 + e][c]);
        *(u16x8*)(ZTout + (size_t)c * ZSTRIDE + r0 + rh * 8) = pk;
    }
}

template<int KS>
static void run(const float* X, const float* S, const float* coeff, float* y,
                uint16_t* ZT0, uint16_t* ZT1, uint16_t* S16, float* P,
                hipStream_t stream) {
    k_prep<<<dim3(512), dim3(256), 0, stream>>>(X, coeff, y, ZT0);
    k_gemm_cv2<KS><<<dim3(128 * KS), dim3(512), 0, stream>>>(S, S16, ZT0, P);
    k_combine<KS, true ><<<dim3(512), dim3(256), 0, stream>>>(P, y, ZT1, coeff, 1);
    k_gemm_bf<KS><<<dim3(128 * KS), dim3(512), 0, stream>>>(S16, ZT1, P);
    k_combine<KS, true ><<<dim3(512), dim3(256), 0, stream>>>(P, y, ZT0, coeff, 2);
    k_gemm_bf<KS><<<dim3(128 * KS), dim3(512), 0, stream>>>(S16, ZT0, P);
    k_combine<KS, false><<<dim3(512), dim3(256), 0, stream>>>(P, y, nullptr, coeff, 3);
}

extern "C" void kernel_launch(void* const* d_in, const int* in_sizes, int n_in,
                              void* d_out, int out_size, void* d_ws, size_t ws_size,
                              hipStream_t stream) {
    const float* X     = (const float*)d_in[0];
    const float* S     = (const float*)d_in[1];
    const float* coeff = (const float*)d_in[2];
    float* y = (float*)d_out;

    uint8_t* ws = (uint8_t*)d_ws;
    const size_t zb     = ((size_t)NF * ZSTRIDE * sizeof(uint16_t) + 255) & ~(size_t)255;
    const size_t s16b   = (size_t)NN * NN * sizeof(uint16_t);
    const size_t base   = 2 * zb + s16b;
    const size_t pslice = (size_t)NN * NF * sizeof(float);
    uint16_t* ZT0 = (uint16_t*)ws;
    uint16_t* ZT1 = (uint16_t*)(ws + zb);
    uint16_t* S16 = (uint16_t*)(ws + 2 * zb);
    float*    P   = (float*)(ws + base);

    if (ws_size >= base + 4 * pslice)
        run<4>(X, S, coeff, y, ZT0, ZT1, S16, P, stream);
    else if (ws_size >= base + 2 * pslice)
        run<2>(X, S, coeff, y, ZT0, ZT1, S16, P, stream);
    else
        run<1>(X, S, coeff, y, ZT0, ZT1, S16, P, stream);
}